// Round 8
// baseline (380.877 us; speedup 1.0000x reference)
//
#include <hip/hip_runtime.h>

#define LDIM 8192
#define HDIM 16
#define DDIM 64
#define NHEADPAIR 64          // N*H
#define ROWSTRIDE 1024        // H*D floats between consecutive l for fixed h
#define KVSZ 4160             // 64*64 KV + 64 ksum
#define EPSF 1e-6f

__device__ __forceinline__ float featmap(float x) {
    // elu(x)+1 : x>0 -> x+1 ; x<=0 -> exp(x)
    return x > 0.0f ? x + 1.0f : __expf(x);
}

// ---------------- Phase 1: partial KV[d][m] and Ksum[d] per (n,h,chunk) -------------
// R2 register outer-product + distance-2 double-buffered prefetch (8 loads in flight
// per wave). NATURAL register allocation (no min-waves clamp!) - R6 proved forcing
// 4 waves/SIMD at ~120 live floats spills to scratch (2.4GB traffic, 6% VALU).
__global__ __launch_bounds__(256) void kv_partial_kernel(
    const float* __restrict__ Kp, const float* __restrict__ Vp,
    float* __restrict__ part, int chunks, int rowsPerChunk)
{
    const int nh   = blockIdx.y;            // 0..63
    const int n    = nh >> 4;
    const int h    = nh & 15;
    const int wave = threadIdx.x >> 6;      // 0..3
    const int lane = threadIdx.x & 63;
    const int chunk = blockIdx.x * 4 + wave;
    const int d0 = (lane & 7) * 8;
    const int m0 = (lane >> 3) * 8;

    const size_t base = (((size_t)n * LDIM) * HDIM + h) * DDIM
                      + (size_t)chunk * rowsPerChunk * ROWSTRIDE;
    const float* Kb = Kp + base;
    const float* Vb = Vp + base;

    float acc[8][8];
    float ksum[8];
#pragma unroll
    for (int i = 0; i < 8; ++i) {
        ksum[i] = 0.0f;
#pragma unroll
        for (int j = 0; j < 8; ++j) acc[i][j] = 0.0f;
    }

    // buffers A (even rows) and B (odd rows), refilled at distance 2
    float4 kaA = *(const float4*)(Kb + d0);
    float4 kbA = *(const float4*)(Kb + d0 + 4);
    float4 vaA = *(const float4*)(Vb + m0);
    float4 vbA = *(const float4*)(Vb + m0 + 4);
    float4 kaB = *(const float4*)(Kb + ROWSTRIDE + d0);
    float4 kbB = *(const float4*)(Kb + ROWSTRIDE + d0 + 4);
    float4 vaB = *(const float4*)(Vb + ROWSTRIDE + m0);
    float4 vbB = *(const float4*)(Vb + ROWSTRIDE + m0 + 4);

    for (int s = 0; s < rowsPerChunk; s += 2) {
        // ---- row s: consume A, refill A with row s+2 ----
        {
            float kf[8] = { featmap(kaA.x), featmap(kaA.y), featmap(kaA.z), featmap(kaA.w),
                            featmap(kbA.x), featmap(kbA.y), featmap(kbA.z), featmap(kbA.w) };
            float vv[8] = { vaA.x, vaA.y, vaA.z, vaA.w, vbA.x, vbA.y, vbA.z, vbA.w };
            const int sn = (s + 2 < rowsPerChunk) ? s + 2 : 0;
            const float* kr = Kb + (size_t)sn * ROWSTRIDE;
            const float* vr = Vb + (size_t)sn * ROWSTRIDE;
            kaA = *(const float4*)(kr + d0);
            kbA = *(const float4*)(kr + d0 + 4);
            vaA = *(const float4*)(vr + m0);
            vbA = *(const float4*)(vr + m0 + 4);
#pragma unroll
            for (int i = 0; i < 8; ++i) {
                ksum[i] += kf[i];
#pragma unroll
                for (int j = 0; j < 8; ++j) acc[i][j] += kf[i] * vv[j];
            }
        }
        // ---- row s+1: consume B, refill B with row s+3 ----
        {
            float kf[8] = { featmap(kaB.x), featmap(kaB.y), featmap(kaB.z), featmap(kaB.w),
                            featmap(kbB.x), featmap(kbB.y), featmap(kbB.z), featmap(kbB.w) };
            float vv[8] = { vaB.x, vaB.y, vaB.z, vaB.w, vbB.x, vbB.y, vbB.z, vbB.w };
            const int sn = (s + 3 < rowsPerChunk) ? s + 3 : 1;
            const float* kr = Kb + (size_t)sn * ROWSTRIDE;
            const float* vr = Vb + (size_t)sn * ROWSTRIDE;
            kaB = *(const float4*)(kr + d0);
            kbB = *(const float4*)(kr + d0 + 4);
            vaB = *(const float4*)(vr + m0);
            vbB = *(const float4*)(vr + m0 + 4);
#pragma unroll
            for (int i = 0; i < 8; ++i) {
                ksum[i] += kf[i];
#pragma unroll
                for (int j = 0; j < 8; ++j) acc[i][j] += kf[i] * vv[j];
            }
        }
    }

    float* p = part + (size_t)(nh * chunks + chunk) * KVSZ;
#pragma unroll
    for (int i = 0; i < 8; ++i) {
        *(float4*)(p + (d0 + i) * 64 + m0) =
            make_float4(acc[i][0], acc[i][1], acc[i][2], acc[i][3]);
        *(float4*)(p + (d0 + i) * 64 + m0 + 4) =
            make_float4(acc[i][4], acc[i][5], acc[i][6], acc[i][7]);
    }
    if (m0 == 0) {
#pragma unroll
        for (int i = 0; i < 8; ++i) p[4096 + d0 + i] = ksum[i];
    }
}

// ---------------- Phase 1b: deterministic parallel reduce of partials ---------------
__global__ __launch_bounds__(256) void kv_reduce_kernel(
    const float* __restrict__ part, float* __restrict__ kvf, int chunks)
{
    const int nh = blockIdx.y;
    const int e  = blockIdx.x * 256 + threadIdx.x;
    if (e >= KVSZ) return;
    float s = 0.0f;
    for (int c = 0; c < chunks; ++c)
        s += part[(size_t)(nh * chunks + c) * KVSZ + e];
    kvf[(size_t)nh * KVSZ + e] = s;
}

// ---------------- Phase 2: out[l][m] = Z * sum_d fm(Q[l,d]) * KV[m][d] ---------------
// Best-known attn: 2 rows x 8 m per thread, natural VGPR (~85).
__global__ __launch_bounds__(256) void attn_out_kernel(
    const float* __restrict__ Qp, const float* __restrict__ kvf,
    float* __restrict__ out)
{
    __shared__ float Bt[64][68];   // Bt[d][m] = KV[m][d]; pad keeps banks spread
    __shared__ float ks[64];

    const int nh = blockIdx.y;
    const int n  = nh >> 4;
    const int h  = nh & 15;
    const float* kv = kvf + (size_t)nh * KVSZ;

    for (int e = threadIdx.x; e < 4096; e += 256) {
        int m = e >> 6, d = e & 63;
        Bt[d][m] = kv[e];
    }
    if (threadIdx.x < 64) ks[threadIdx.x] = kv[4096 + threadIdx.x];
    __syncthreads();

    const int wave = threadIdx.x >> 6;
    const int lane = threadIdx.x & 63;
    const int mg = lane & 7;
    const int lg = lane >> 3;
    const int m0 = mg * 8;
    const int l0 = blockIdx.x * 64 + wave * 16 + lg * 2;   // 2 rows per thread

    const float* Qb = Qp + (((size_t)n * LDIM) * HDIM + h) * DDIM;

    float acc[2][8];
    float zacc[2];
#pragma unroll
    for (int i = 0; i < 2; ++i) {
        zacc[i] = 0.0f;
#pragma unroll
        for (int j = 0; j < 8; ++j) acc[i][j] = 0.0f;
    }

#pragma unroll
    for (int c8 = 0; c8 < 8; ++c8) {
        const int dd = c8 * 8;
        float qf[2][8];
#pragma unroll
        for (int i = 0; i < 2; ++i) {
            const float* qr = Qb + (size_t)(l0 + i) * ROWSTRIDE + dd;
            float4 a = *(const float4*)(qr);
            float4 b = *(const float4*)(qr + 4);
            qf[i][0] = featmap(a.x); qf[i][1] = featmap(a.y);
            qf[i][2] = featmap(a.z); qf[i][3] = featmap(a.w);
            qf[i][4] = featmap(b.x); qf[i][5] = featmap(b.y);
            qf[i][6] = featmap(b.z); qf[i][7] = featmap(b.w);
        }
#pragma unroll
        for (int j = 0; j < 8; ++j) {
            const float ksj = ks[dd + j];
            float4 b0 = *(const float4*)(&Bt[dd + j][m0]);
            float4 b1 = *(const float4*)(&Bt[dd + j][m0 + 4]);
#pragma unroll
            for (int i = 0; i < 2; ++i) {
                const float q = qf[i][j];
                zacc[i]   += q * ksj;
                acc[i][0] += q * b0.x; acc[i][1] += q * b0.y;
                acc[i][2] += q * b0.z; acc[i][3] += q * b0.w;
                acc[i][4] += q * b1.x; acc[i][5] += q * b1.y;
                acc[i][6] += q * b1.z; acc[i][7] += q * b1.w;
            }
        }
    }

#pragma unroll
    for (int i = 0; i < 2; ++i) {
        const float z = 1.0f / (zacc[i] + EPSF);
        float* orow = out + (((size_t)n * LDIM + (l0 + i)) * HDIM + h) * DDIM + m0;
        *(float4*)(orow)     = make_float4(acc[i][0] * z, acc[i][1] * z,
                                           acc[i][2] * z, acc[i][3] * z);
        *(float4*)(orow + 4) = make_float4(acc[i][4] * z, acc[i][5] * z,
                                           acc[i][6] * z, acc[i][7] * z);
    }
}

extern "C" void kernel_launch(void* const* d_in, const int* in_sizes, int n_in,
                              void* d_out, int out_size, void* d_ws, size_t ws_size,
                              hipStream_t stream) {
    const float* Q = (const float*)d_in[0];
    const float* K = (const float*)d_in[1];
    const float* V = (const float*)d_in[2];
    float* out = (float*)d_out;
    float* ws  = (float*)d_ws;

    // pick chunk count (per head-pair) that fits the workspace
    int chunks = 64;
    while (chunks > 4 &&
           ((size_t)NHEADPAIR * chunks + NHEADPAIR) * KVSZ * sizeof(float) > ws_size)
        chunks >>= 1;
    const int rowsPerChunk = LDIM / chunks;

    float* part = ws;
    float* kvf  = ws + (size_t)NHEADPAIR * chunks * KVSZ;

    dim3 g1(chunks / 4, NHEADPAIR);
    kv_partial_kernel<<<g1, 256, 0, stream>>>(K, V, part, chunks, rowsPerChunk);
    dim3 gr((KVSZ + 255) / 256, NHEADPAIR);
    kv_reduce_kernel<<<gr, 256, 0, stream>>>(part, kvf, chunks);
    dim3 g2(LDIM / 64, NHEADPAIR);
    attn_out_kernel<<<g2, 256, 0, stream>>>(Q, kvf, out);
}

// Round 9
// 270.063 us; speedup vs baseline: 1.4103x; 1.4103x over previous
//
#include <hip/hip_runtime.h>

#define LDIM 8192
#define HDIM 16
#define DDIM 64
#define NHEADPAIR 64          // N*H
#define ROWSTRIDE 1024        // H*D floats between consecutive l for fixed h
#define KVSZ 4160             // 64*64 KV + 64 ksum
#define EPSF 1e-6f
#define TROWS 32              // rows per staged tile

__device__ __forceinline__ float featmap(float x) {
    // elu(x)+1 : x>0 -> x+1 ; x<=0 -> exp(x)
    return x > 0.0f ? x + 1.0f : __expf(x);
}

// async global->LDS, 16B per lane, LDS dest = uniform base + lane*16
__device__ __forceinline__ void gload_lds16(const float* g, float* l) {
    __builtin_amdgcn_global_load_lds(
        (const __attribute__((address_space(1))) void*)g,
        (__attribute__((address_space(3))) void*)l, 16, 0, 0);
}

// ---------------- Phase 1: partial KV[d][m] and Ksum[d] -----------------------------
// Block-cooperative, global_load_lds staged (m97 pattern): a 32-row tile's loads are
// issued async and drain ONCE per tile at the barrier (amortized 32x vs per-row drain
// that capped R2/R7 at 156us). Wave w computes rows 8w..8w+7 of each tile into its own
// 8x8 register tile and its own partial slot (no cross-wave merge).
__global__ __launch_bounds__(256) void kv_partial_kernel(
    const float* __restrict__ Kp, const float* __restrict__ Vp,
    float* __restrict__ part, int chunks, int rowsPerBlock)
{
    __shared__ float Klds[2][TROWS][64];
    __shared__ float Vlds[2][TROWS][64];

    const int nh   = blockIdx.y;            // 0..63
    const int n    = nh >> 4;
    const int h    = nh & 15;
    const int wave = threadIdx.x >> 6;      // 0..3
    const int lane = threadIdx.x & 63;
    const int d0 = (lane & 7) * 8;
    const int m0 = (lane >> 3) * 8;

    const size_t base = (((size_t)n * LDIM) * HDIM + h) * DDIM
                      + (size_t)blockIdx.x * rowsPerBlock * ROWSTRIDE;
    const float* Kb = Kp + base;
    const float* Vb = Vp + base;
    const int NT = rowsPerBlock / TROWS;

    // staging map: lane -> (row-in-quad, 16B granule)
    const int rl = lane >> 4;               // 0..3
    const int c4 = (lane & 15) * 4;         // float offset

    float acc[8][8];
    float ksum[8];
#pragma unroll
    for (int i = 0; i < 8; ++i) {
        ksum[i] = 0.0f;
#pragma unroll
        for (int j = 0; j < 8; ++j) acc[i][j] = 0.0f;
    }

    // prologue: stage tile 0 into buf 0
#pragma unroll
    for (int i = 0; i < 2; ++i) {
        const int row = wave * 8 + i * 4;   // uniform per wave
        gload_lds16(Kb + (size_t)(row + rl) * ROWSTRIDE + c4, &Klds[0][row][0]);
        gload_lds16(Vb + (size_t)(row + rl) * ROWSTRIDE + c4, &Vlds[0][row][0]);
    }
    __syncthreads();

    int buf = 0;
    for (int t = 0; t < NT; ++t) {
        if (t + 1 < NT) {
            const size_t tb = (size_t)(t + 1) * TROWS;
#pragma unroll
            for (int i = 0; i < 2; ++i) {
                const int row = wave * 8 + i * 4;
                gload_lds16(Kb + (tb + row + rl) * ROWSTRIDE + c4, &Klds[buf ^ 1][row][0]);
                gload_lds16(Vb + (tb + row + rl) * ROWSTRIDE + c4, &Vlds[buf ^ 1][row][0]);
            }
        }

        // compute: wave w consumes rows 8w..8w+7 of current tile
#pragma unroll
        for (int r = 0; r < 8; ++r) {
            const int row = wave * 8 + r;
            float4 k0 = *(const float4*)&Klds[buf][row][d0];
            float4 k1 = *(const float4*)&Klds[buf][row][d0 + 4];
            float4 v0 = *(const float4*)&Vlds[buf][row][m0];
            float4 v1 = *(const float4*)&Vlds[buf][row][m0 + 4];
            float kf[8] = { featmap(k0.x), featmap(k0.y), featmap(k0.z), featmap(k0.w),
                            featmap(k1.x), featmap(k1.y), featmap(k1.z), featmap(k1.w) };
            float vv[8] = { v0.x, v0.y, v0.z, v0.w, v1.x, v1.y, v1.z, v1.w };
#pragma unroll
            for (int i = 0; i < 8; ++i) {
                ksum[i] += kf[i];
#pragma unroll
                for (int j = 0; j < 8; ++j) acc[i][j] += kf[i] * vv[j];
            }
        }

        __syncthreads();   // drains stage of t+1; protects buf reuse
        buf ^= 1;
    }

    const int chunk = blockIdx.x * 4 + wave;   // per-wave partial slot
    float* p = part + (size_t)(nh * chunks + chunk) * KVSZ;
#pragma unroll
    for (int i = 0; i < 8; ++i) {
        *(float4*)(p + (d0 + i) * 64 + m0) =
            make_float4(acc[i][0], acc[i][1], acc[i][2], acc[i][3]);
        *(float4*)(p + (d0 + i) * 64 + m0 + 4) =
            make_float4(acc[i][4], acc[i][5], acc[i][6], acc[i][7]);
    }
    if (m0 == 0) {
#pragma unroll
        for (int i = 0; i < 8; ++i) p[4096 + d0 + i] = ksum[i];
    }
}

// ---------------- Phase 1b: deterministic parallel reduce of partials ---------------
__global__ __launch_bounds__(256) void kv_reduce_kernel(
    const float* __restrict__ part, float* __restrict__ kvf, int chunks)
{
    const int nh = blockIdx.y;
    const int e  = blockIdx.x * 256 + threadIdx.x;
    if (e >= KVSZ) return;
    float s = 0.0f;
    for (int c = 0; c < chunks; ++c)
        s += part[(size_t)(nh * chunks + c) * KVSZ + e];
    kvf[(size_t)nh * KVSZ + e] = s;
}

// ---------------- Phase 2: out[l][m] = Z * sum_d fm(Q[l,d]) * KV[m][d] ---------------
// Best-known attn: 2 rows x 8 m per thread, natural VGPR (~85).
__global__ __launch_bounds__(256) void attn_out_kernel(
    const float* __restrict__ Qp, const float* __restrict__ kvf,
    float* __restrict__ out)
{
    __shared__ float Bt[64][68];   // Bt[d][m] = KV[m][d]; pad keeps banks spread
    __shared__ float ks[64];

    const int nh = blockIdx.y;
    const int n  = nh >> 4;
    const int h  = nh & 15;
    const float* kv = kvf + (size_t)nh * KVSZ;

    for (int e = threadIdx.x; e < 4096; e += 256) {
        int m = e >> 6, d = e & 63;
        Bt[d][m] = kv[e];
    }
    if (threadIdx.x < 64) ks[threadIdx.x] = kv[4096 + threadIdx.x];
    __syncthreads();

    const int wave = threadIdx.x >> 6;
    const int lane = threadIdx.x & 63;
    const int mg = lane & 7;
    const int lg = lane >> 3;
    const int m0 = mg * 8;
    const int l0 = blockIdx.x * 64 + wave * 16 + lg * 2;   // 2 rows per thread

    const float* Qb = Qp + (((size_t)n * LDIM) * HDIM + h) * DDIM;

    float acc[2][8];
    float zacc[2];
#pragma unroll
    for (int i = 0; i < 2; ++i) {
        zacc[i] = 0.0f;
#pragma unroll
        for (int j = 0; j < 8; ++j) acc[i][j] = 0.0f;
    }

#pragma unroll
    for (int c8 = 0; c8 < 8; ++c8) {
        const int dd = c8 * 8;
        float qf[2][8];
#pragma unroll
        for (int i = 0; i < 2; ++i) {
            const float* qr = Qb + (size_t)(l0 + i) * ROWSTRIDE + dd;
            float4 a = *(const float4*)(qr);
            float4 b = *(const float4*)(qr + 4);
            qf[i][0] = featmap(a.x); qf[i][1] = featmap(a.y);
            qf[i][2] = featmap(a.z); qf[i][3] = featmap(a.w);
            qf[i][4] = featmap(b.x); qf[i][5] = featmap(b.y);
            qf[i][6] = featmap(b.z); qf[i][7] = featmap(b.w);
        }
#pragma unroll
        for (int j = 0; j < 8; ++j) {
            const float ksj = ks[dd + j];
            float4 b0 = *(const float4*)(&Bt[dd + j][m0]);
            float4 b1 = *(const float4*)(&Bt[dd + j][m0 + 4]);
#pragma unroll
            for (int i = 0; i < 2; ++i) {
                const float q = qf[i][j];
                zacc[i]   += q * ksj;
                acc[i][0] += q * b0.x; acc[i][1] += q * b0.y;
                acc[i][2] += q * b0.z; acc[i][3] += q * b0.w;
                acc[i][4] += q * b1.x; acc[i][5] += q * b1.y;
                acc[i][6] += q * b1.z; acc[i][7] += q * b1.w;
            }
        }
    }

#pragma unroll
    for (int i = 0; i < 2; ++i) {
        const float z = 1.0f / (zacc[i] + EPSF);
        float* orow = out + (((size_t)n * LDIM + (l0 + i)) * HDIM + h) * DDIM + m0;
        *(float4*)(orow)     = make_float4(acc[i][0] * z, acc[i][1] * z,
                                           acc[i][2] * z, acc[i][3] * z);
        *(float4*)(orow + 4) = make_float4(acc[i][4] * z, acc[i][5] * z,
                                           acc[i][6] * z, acc[i][7] * z);
    }
}

extern "C" void kernel_launch(void* const* d_in, const int* in_sizes, int n_in,
                              void* d_out, int out_size, void* d_ws, size_t ws_size,
                              hipStream_t stream) {
    const float* Q = (const float*)d_in[0];
    const float* K = (const float*)d_in[1];
    const float* V = (const float*)d_in[2];
    float* out = (float*)d_out;
    float* ws  = (float*)d_ws;

    // pick chunk count (per head-pair) that fits the workspace
    int chunks = 64;
    while (chunks > 4 &&
           ((size_t)NHEADPAIR * chunks + NHEADPAIR) * KVSZ * sizeof(float) > ws_size)
        chunks >>= 1;
    const int blocksPerNH = chunks / 4;            // one block = 4 wave-slots
    const int rowsPerBlock = LDIM / blocksPerNH;   // divisible by 32 for all chunk cfgs

    float* part = ws;
    float* kvf  = ws + (size_t)NHEADPAIR * chunks * KVSZ;

    dim3 g1(blocksPerNH, NHEADPAIR);
    kv_partial_kernel<<<g1, 256, 0, stream>>>(K, V, part, chunks, rowsPerBlock);
    dim3 gr((KVSZ + 255) / 256, NHEADPAIR);
    kv_reduce_kernel<<<gr, 256, 0, stream>>>(part, kvf, chunks);
    dim3 g2(LDIM / 64, NHEADPAIR);
    attn_out_kernel<<<g2, 256, 0, stream>>>(Q, kvf, out);
}

// Round 10
// 206.343 us; speedup vs baseline: 1.8458x; 1.3088x over previous
//
#include <hip/hip_runtime.h>
#include <hip/hip_bf16.h>

#define LDIM 8192
#define HDIM 16
#define DDIM 64
#define NHEADPAIR 64          // N*H
#define ROWSTRIDE 1024        // H*D floats between consecutive l for fixed h
#define KVSZ 4160             // 64*64 KV + 64 ksum
#define EPSF 1e-6f
#define TROWS 32              // rows per staged tile (phase 1)

typedef float f32x4 __attribute__((ext_vector_type(4)));
typedef short s16x8 __attribute__((ext_vector_type(8)));   // 8 bf16 (4 VGPRs)

__device__ __forceinline__ float featmap(float x) {
    // elu(x)+1 : x>0 -> x+1 ; x<=0 -> exp(x)
    return x > 0.0f ? x + 1.0f : __expf(x);
}

__device__ __forceinline__ unsigned int pack_bf16x2(float a, float b) {
    union { __hip_bfloat162 h; unsigned int u; } x;
    x.h = __float22bfloat162_rn(make_float2(a, b));   // elem0 -> low 16 bits
    return x.u;
}

// async global->LDS, 16B per lane, LDS dest = uniform base + lane*16
__device__ __forceinline__ void gload_lds16(const float* g, float* l) {
    __builtin_amdgcn_global_load_lds(
        (const __attribute__((address_space(1))) void*)g,
        (__attribute__((address_space(3))) void*)l, 16, 0, 0);
}

// ---------------- Phase 1: partial KV[a][b] and Ksum[a] (a=K-axis, b=V-axis) --------
// Unchanged from R8 (measured 149us): global_load_lds staged, drain once per 32 rows.
__global__ __launch_bounds__(256) void kv_partial_kernel(
    const float* __restrict__ Kp, const float* __restrict__ Vp,
    float* __restrict__ part, int chunks, int rowsPerBlock)
{
    __shared__ float Klds[2][TROWS][64];
    __shared__ float Vlds[2][TROWS][64];

    const int nh   = blockIdx.y;
    const int n    = nh >> 4;
    const int h    = nh & 15;
    const int wave = threadIdx.x >> 6;
    const int lane = threadIdx.x & 63;
    const int d0 = (lane & 7) * 8;
    const int m0 = (lane >> 3) * 8;

    const size_t base = (((size_t)n * LDIM) * HDIM + h) * DDIM
                      + (size_t)blockIdx.x * rowsPerBlock * ROWSTRIDE;
    const float* Kb = Kp + base;
    const float* Vb = Vp + base;
    const int NT = rowsPerBlock / TROWS;

    const int rl = lane >> 4;
    const int c4 = (lane & 15) * 4;

    float acc[8][8];
    float ksum[8];
#pragma unroll
    for (int i = 0; i < 8; ++i) {
        ksum[i] = 0.0f;
#pragma unroll
        for (int j = 0; j < 8; ++j) acc[i][j] = 0.0f;
    }

#pragma unroll
    for (int i = 0; i < 2; ++i) {
        const int row = wave * 8 + i * 4;
        gload_lds16(Kb + (size_t)(row + rl) * ROWSTRIDE + c4, &Klds[0][row][0]);
        gload_lds16(Vb + (size_t)(row + rl) * ROWSTRIDE + c4, &Vlds[0][row][0]);
    }
    __syncthreads();

    int buf = 0;
    for (int t = 0; t < NT; ++t) {
        if (t + 1 < NT) {
            const size_t tb = (size_t)(t + 1) * TROWS;
#pragma unroll
            for (int i = 0; i < 2; ++i) {
                const int row = wave * 8 + i * 4;
                gload_lds16(Kb + (tb + row + rl) * ROWSTRIDE + c4, &Klds[buf ^ 1][row][0]);
                gload_lds16(Vb + (tb + row + rl) * ROWSTRIDE + c4, &Vlds[buf ^ 1][row][0]);
            }
        }

#pragma unroll
        for (int r = 0; r < 8; ++r) {
            const int row = wave * 8 + r;
            float4 k0 = *(const float4*)&Klds[buf][row][d0];
            float4 k1 = *(const float4*)&Klds[buf][row][d0 + 4];
            float4 v0 = *(const float4*)&Vlds[buf][row][m0];
            float4 v1 = *(const float4*)&Vlds[buf][row][m0 + 4];
            float kf[8] = { featmap(k0.x), featmap(k0.y), featmap(k0.z), featmap(k0.w),
                            featmap(k1.x), featmap(k1.y), featmap(k1.z), featmap(k1.w) };
            float vv[8] = { v0.x, v0.y, v0.z, v0.w, v1.x, v1.y, v1.z, v1.w };
#pragma unroll
            for (int i = 0; i < 8; ++i) {
                ksum[i] += kf[i];
#pragma unroll
                for (int j = 0; j < 8; ++j) acc[i][j] += kf[i] * vv[j];
            }
        }

        __syncthreads();
        buf ^= 1;
    }

    const int chunk = blockIdx.x * 4 + wave;
    float* p = part + (size_t)(nh * chunks + chunk) * KVSZ;
#pragma unroll
    for (int i = 0; i < 8; ++i) {
        *(float4*)(p + (d0 + i) * 64 + m0) =
            make_float4(acc[i][0], acc[i][1], acc[i][2], acc[i][3]);
        *(float4*)(p + (d0 + i) * 64 + m0 + 4) =
            make_float4(acc[i][4], acc[i][5], acc[i][6], acc[i][7]);
    }
    if (m0 == 0) {
#pragma unroll
        for (int i = 0; i < 8; ++i) p[4096 + d0 + i] = ksum[i];
    }
}

// ---------------- Phase 1b: reduce partials, emit bf16 KV + ksum --------------------
__global__ __launch_bounds__(256) void kv_reduce_kernel(
    const float* __restrict__ part, unsigned short* __restrict__ kvh, int chunks)
{
    const int nh = blockIdx.y;
    const int e  = blockIdx.x * 256 + threadIdx.x;
    if (e >= KVSZ) return;
    float s = 0.0f;
    for (int c = 0; c < chunks; ++c)
        s += part[(size_t)(nh * chunks + c) * KVSZ + e];
    union { __hip_bfloat16 h; unsigned short u; } cv;
    cv.h = __float2bfloat16(s);
    kvh[(size_t)nh * KVSZ + e] = cv.u;
}

// ---------------- Phase 2 (MFMA): out[l][m] = Z * sum_d fmQ[l][d] * KV[m][d] --------
// A-frag: fmQ rows (k=d contiguous). B-frag: kvh row m (contraction axis contiguous -
// the reference's label swap makes this transpose-free). Z via ksum-broadcast B frag
// whose D shares the acc row layout. 16x16x32 bf16 MFMA, fp32 accum.
__global__ __launch_bounds__(256) void attn_mfma_kernel(
    const float* __restrict__ Qp, const unsigned short* __restrict__ kvh,
    float* __restrict__ out)
{
    __shared__ unsigned int kvU[64][36];   // row m, 32 data uints (64 bf16) + pad
    __shared__ unsigned int ksU[36];
    __shared__ unsigned int qU[128][36];   // row l, fm(Q) bf16

    const int nh = blockIdx.y;
    const int n  = nh >> 4;
    const int h  = nh & 15;
    const int t  = threadIdx.x;

    // ---- stage KV (2048 uints) + ksum (32 uints) ----
    {
        const unsigned int* kvg = (const unsigned int*)(kvh + (size_t)nh * KVSZ);
        const int r  = t >> 2;
        const int c0 = (t & 3) * 8;
        uint4 x = *(const uint4*)(kvg + r * 32 + c0);
        uint4 y = *(const uint4*)(kvg + r * 32 + c0 + 4);
        *(uint4*)&kvU[r][c0]     = x;
        *(uint4*)&kvU[r][c0 + 4] = y;
        if (t < 32) ksU[t] = kvg[2048 + t];
    }

    // ---- stage fm(Q) for this block's 128 rows ----
    {
        const int qr = t >> 1;
        const int qc = (t & 1) * 32;
        const float* qg = Qp + ((((size_t)n * LDIM) + (size_t)blockIdx.x * 128 + qr)
                                * HDIM + h) * DDIM + qc;
        unsigned int q[16];
#pragma unroll
        for (int j = 0; j < 8; ++j) {
            float4 f = *(const float4*)(qg + j * 4);
            q[2 * j]     = pack_bf16x2(featmap(f.x), featmap(f.y));
            q[2 * j + 1] = pack_bf16x2(featmap(f.z), featmap(f.w));
        }
        uint4* dst = (uint4*)&qU[qr][(t & 1) * 16];
        dst[0] = make_uint4(q[0],  q[1],  q[2],  q[3]);
        dst[1] = make_uint4(q[4],  q[5],  q[6],  q[7]);
        dst[2] = make_uint4(q[8],  q[9],  q[10], q[11]);
        dst[3] = make_uint4(q[12], q[13], q[14], q[15]);
    }
    __syncthreads();

    const int wave = t >> 6;
    const int lane = t & 63;
    const int fr = lane & 15;      // A: row ; B: col ; D: col
    const int fk = lane >> 4;      // k-group (8 bf16 each)

    // loop-invariant B fragments (KV rows + ksum broadcast)
    s16x8 bF[4][2], kF[2];
#pragma unroll
    for (int mt = 0; mt < 4; ++mt)
#pragma unroll
        for (int kk = 0; kk < 2; ++kk)
            bF[mt][kk] = *(const s16x8*)&kvU[mt * 16 + fr][kk * 16 + fk * 4];
#pragma unroll
    for (int kk = 0; kk < 2; ++kk)
        kF[kk] = *(const s16x8*)&ksU[kk * 16 + fk * 4];

    f32x4 acc[2][4];
    f32x4 zac[2];
#pragma unroll
    for (int lt = 0; lt < 2; ++lt) {
        zac[lt] = (f32x4){0.f, 0.f, 0.f, 0.f};
#pragma unroll
        for (int mt = 0; mt < 4; ++mt) acc[lt][mt] = (f32x4){0.f, 0.f, 0.f, 0.f};
    }

#pragma unroll
    for (int kk = 0; kk < 2; ++kk) {
#pragma unroll
        for (int lt = 0; lt < 2; ++lt) {
            s16x8 A = *(const s16x8*)&qU[wave * 32 + lt * 16 + fr][kk * 16 + fk * 4];
            zac[lt] = __builtin_amdgcn_mfma_f32_16x16x32_bf16(A, kF[kk], zac[lt], 0, 0, 0);
#pragma unroll
            for (int mt = 0; mt < 4; ++mt)
                acc[lt][mt] = __builtin_amdgcn_mfma_f32_16x16x32_bf16(
                    A, bF[mt][kk], acc[lt][mt], 0, 0, 0);
        }
    }

    // ---- epilogue: D row = 4*fk + reg (l), D col = fr (m) ----
#pragma unroll
    for (int lt = 0; lt < 2; ++lt) {
#pragma unroll
        for (int reg = 0; reg < 4; ++reg) {
            const int row = blockIdx.x * 128 + wave * 32 + lt * 16 + fk * 4 + reg;
            const float z = 1.0f / (zac[lt][reg] + EPSF);
            float* orow = out + (((size_t)n * LDIM + row) * HDIM + h) * DDIM;
#pragma unroll
            for (int mt = 0; mt < 4; ++mt)
                orow[mt * 16 + fr] = acc[lt][mt][reg] * z;
        }
    }
}

extern "C" void kernel_launch(void* const* d_in, const int* in_sizes, int n_in,
                              void* d_out, int out_size, void* d_ws, size_t ws_size,
                              hipStream_t stream) {
    const float* Q = (const float*)d_in[0];
    const float* K = (const float*)d_in[1];
    const float* V = (const float*)d_in[2];
    float* out = (float*)d_out;
    float* ws  = (float*)d_ws;

    int chunks = 64;
    while (chunks > 4 &&
           (size_t)NHEADPAIR * chunks * KVSZ * sizeof(float)
             + (size_t)NHEADPAIR * KVSZ * sizeof(unsigned short) > ws_size)
        chunks >>= 1;
    const int blocksPerNH = chunks / 4;
    const int rowsPerBlock = LDIM / blocksPerNH;

    float* part = ws;
    unsigned short* kvh = (unsigned short*)(ws + (size_t)NHEADPAIR * chunks * KVSZ);

    dim3 g1(blocksPerNH, NHEADPAIR);
    kv_partial_kernel<<<g1, 256, 0, stream>>>(K, V, part, chunks, rowsPerBlock);
    dim3 gr((KVSZ + 255) / 256, NHEADPAIR);
    kv_reduce_kernel<<<gr, 256, 0, stream>>>(part, kvh, chunks);
    dim3 g2(LDIM / 128, NHEADPAIR);
    attn_mfma_kernel<<<g2, 256, 0, stream>>>(Q, kvh, out);
}

// Round 11
// 146.297 us; speedup vs baseline: 2.6034x; 1.4104x over previous
//
#include <hip/hip_runtime.h>
#include <hip/hip_bf16.h>

#define LDIM 8192
#define HDIM 16
#define DDIM 64
#define NHEADPAIR 64          // N*H
#define ROWSTRIDE 1024        // H*D floats between consecutive l for fixed h
#define KVSZ 4160             // 64*64 KV + 64 ksum
#define EPSF 1e-6f
#define TROWS 32              // s-rows per staged tile

typedef float f32x4 __attribute__((ext_vector_type(4)));
typedef short s16x8 __attribute__((ext_vector_type(8)));   // 8 bf16 (4 VGPRs)

__device__ __forceinline__ float featmap(float x) {
    // elu(x)+1 : x>0 -> x+1 ; x<=0 -> exp(x)
    return x > 0.0f ? x + 1.0f : __expf(x);
}

__device__ __forceinline__ unsigned int pack_bf16x2(float a, float b) {
    union { __hip_bfloat162 h; unsigned int u; } x;
    x.h = __float22bfloat162_rn(make_float2(a, b));   // elem0 -> low 16 bits
    return x.u;
}

// swizzle: XOR bits 2-3 of the s-pair index with d bits 3-4; multiple of 4 so a
// 4-uint (16B) read at rp=fk*4 stays contiguous & aligned. Breaks the
// d-stride-64B all-same-bank pattern on ds_write (8-way -> 4-way max).
__device__ __forceinline__ int swz(int d) { return ((d >> 3) & 3) << 2; }

// ---------------- Phase 1 (MFMA): partial KV[d][m], Ksum[d] per (n,h,chunk) ---------
// KV = sum_s fm(K[s,d]) * V[s,m]: contraction axis s. Stage 32-row tiles transposed
// to bf16 [d][s] / [m][s] in LDS (featmap applied once at stage time), then
// per wave: 1 A-frag + 4 B-frags + ones-frag -> 5 MFMAs per tile.
__global__ __launch_bounds__(256) void kv_mfma_kernel(
    const float* __restrict__ Kp, const float* __restrict__ Vp,
    float* __restrict__ part, int chunks, int rowsPerBlock)
{
    __shared__ unsigned int KT[2][64 * 16];   // [d][16 s-pair uints] (swizzled)
    __shared__ unsigned int VT[2][64 * 16];   // [m][16 s-pair uints]

    const int nh   = blockIdx.y;
    const int n    = nh >> 4;
    const int h    = nh & 15;
    const int t    = threadIdx.x;
    const int wave = t >> 6;
    const int lane = t & 63;

    const size_t base = (((size_t)n * LDIM) * HDIM + h) * DDIM
                      + (size_t)blockIdx.x * rowsPerBlock * ROWSTRIDE;

    // staging map: threads 0-127 stage K (waves 0-1, featmap), 128-255 stage V.
    const bool isK = (t < 128);
    const int  u   = t & 127;
    const int  dg  = u & 7;          // col-group: cols dg*8 .. dg*8+7
    const int  rp  = u >> 3;         // s-pair 0..15 (rows 2rp, 2rp+1)
    const float* Sb = (isK ? Kp : Vp) + base + (size_t)(2 * rp) * ROWSTRIDE + dg * 8;

    const int NT = rowsPerBlock / TROWS;

    f32x4 acc[4];                     // 4 m-tiles x 4 regs (d rows)
    f32x4 zac;                        // ksum
#pragma unroll
    for (int mt = 0; mt < 4; ++mt) acc[mt] = (f32x4){0.f, 0.f, 0.f, 0.f};
    zac = (f32x4){0.f, 0.f, 0.f, 0.f};

    s16x8 ones;
#pragma unroll
    for (int i = 0; i < 8; ++i) ones[i] = (short)0x3F80;   // bf16 1.0

    // compute-side frag coords (validated layout from attn kernel)
    const int fr = lane & 15;
    const int fk = lane >> 4;
    const int d0 = wave * 16;
    const int raddr = (d0 + fr) * 16 + ((fk * 4) ^ swz(d0 + fr));

    float4 a0, a1, b0, b1;
    // prologue: load tile 0
    a0 = *(const float4*)(Sb);
    a1 = *(const float4*)(Sb + 4);
    b0 = *(const float4*)(Sb + ROWSTRIDE);
    b1 = *(const float4*)(Sb + ROWSTRIDE + 4);
    {
        unsigned int* T = isK ? &KT[0][0] : &VT[0][0];
        float fa[8] = { a0.x, a0.y, a0.z, a0.w, a1.x, a1.y, a1.z, a1.w };
        float fb[8] = { b0.x, b0.y, b0.z, b0.w, b1.x, b1.y, b1.z, b1.w };
        if (isK) {
#pragma unroll
            for (int j = 0; j < 8; ++j) { fa[j] = featmap(fa[j]); fb[j] = featmap(fb[j]); }
        }
#pragma unroll
        for (int j = 0; j < 8; ++j) {
            const int d = dg * 8 + j;
            T[d * 16 + (rp ^ swz(d))] = pack_bf16x2(fa[j], fb[j]);
        }
    }
    __syncthreads();

    int buf = 0;
    for (int tt = 0; tt < NT; ++tt) {
        const bool more = (tt + 1 < NT);
        if (more) {
            const float* S = Sb + (size_t)(tt + 1) * TROWS * ROWSTRIDE;
            a0 = *(const float4*)(S);
            a1 = *(const float4*)(S + 4);
            b0 = *(const float4*)(S + ROWSTRIDE);
            b1 = *(const float4*)(S + ROWSTRIDE + 4);
        }

        // ---- compute current tile: 5 ds_read_b128 + 5 MFMAs per wave ----
        {
            s16x8 A = *(const s16x8*)&KT[buf][raddr];
            zac = __builtin_amdgcn_mfma_f32_16x16x32_bf16(A, ones, zac, 0, 0, 0);
#pragma unroll
            for (int mt = 0; mt < 4; ++mt) {
                const int m = mt * 16 + fr;
                s16x8 B = *(const s16x8*)&VT[buf][m * 16 + ((fk * 4) ^ swz(m))];
                acc[mt] = __builtin_amdgcn_mfma_f32_16x16x32_bf16(A, B, acc[mt], 0, 0, 0);
            }
        }

        // ---- transform + write next tile into other buffer ----
        if (more) {
            unsigned int* T = isK ? &KT[buf ^ 1][0] : &VT[buf ^ 1][0];
            float fa[8] = { a0.x, a0.y, a0.z, a0.w, a1.x, a1.y, a1.z, a1.w };
            float fb[8] = { b0.x, b0.y, b0.z, b0.w, b1.x, b1.y, b1.z, b1.w };
            if (isK) {
#pragma unroll
                for (int j = 0; j < 8; ++j) { fa[j] = featmap(fa[j]); fb[j] = featmap(fb[j]); }
            }
#pragma unroll
            for (int j = 0; j < 8; ++j) {
                const int d = dg * 8 + j;
                T[d * 16 + (rp ^ swz(d))] = pack_bf16x2(fa[j], fb[j]);
            }
        }
        __syncthreads();
        buf ^= 1;
    }

    // ---- epilogue: D row = d within band (fk*4+reg), D col = m (fr) ----
    float* p = part + (size_t)(nh * chunks + blockIdx.x) * KVSZ;
#pragma unroll
    for (int mt = 0; mt < 4; ++mt) {
#pragma unroll
        for (int reg = 0; reg < 4; ++reg) {
            p[(d0 + fk * 4 + reg) * 64 + mt * 16 + fr] = acc[mt][reg];
        }
    }
    if (fr == 0) {
#pragma unroll
        for (int reg = 0; reg < 4; ++reg)
            p[4096 + d0 + fk * 4 + reg] = zac[reg];
    }
}

// ---------------- Phase 1b: reduce partials, emit bf16 KV + ksum --------------------
__global__ __launch_bounds__(256) void kv_reduce_kernel(
    const float* __restrict__ part, unsigned short* __restrict__ kvh, int chunks)
{
    const int nh = blockIdx.y;
    const int e  = blockIdx.x * 256 + threadIdx.x;
    if (e >= KVSZ) return;
    float s = 0.0f;
    for (int c = 0; c < chunks; ++c)
        s += part[(size_t)(nh * chunks + c) * KVSZ + e];
    union { __hip_bfloat16 h; unsigned short u; } cv;
    cv.h = __float2bfloat16(s);
    kvh[(size_t)nh * KVSZ + e] = cv.u;
}

// ---------------- Phase 2 (MFMA): out[l][m] = Z * sum_d fmQ[l][d] * KV[m][d] --------
// Unchanged from R10 (validated, ~45us).
__global__ __launch_bounds__(256) void attn_mfma_kernel(
    const float* __restrict__ Qp, const unsigned short* __restrict__ kvh,
    float* __restrict__ out)
{
    __shared__ unsigned int kvU[64][36];
    __shared__ unsigned int ksU[36];
    __shared__ unsigned int qU[128][36];

    const int nh = blockIdx.y;
    const int n  = nh >> 4;
    const int h  = nh & 15;
    const int t  = threadIdx.x;

    {
        const unsigned int* kvg = (const unsigned int*)(kvh + (size_t)nh * KVSZ);
        const int r  = t >> 2;
        const int c0 = (t & 3) * 8;
        uint4 x = *(const uint4*)(kvg + r * 32 + c0);
        uint4 y = *(const uint4*)(kvg + r * 32 + c0 + 4);
        *(uint4*)&kvU[r][c0]     = x;
        *(uint4*)&kvU[r][c0 + 4] = y;
        if (t < 32) ksU[t] = kvg[2048 + t];
    }

    {
        const int qr = t >> 1;
        const float* qg = Qp + ((((size_t)n * LDIM) + (size_t)blockIdx.x * 128 + qr)
                                * HDIM + h) * DDIM + (t & 1) * 32;
        unsigned int q[16];
#pragma unroll
        for (int j = 0; j < 8; ++j) {
            float4 f = *(const float4*)(qg + j * 4);
            q[2 * j]     = pack_bf16x2(featmap(f.x), featmap(f.y));
            q[2 * j + 1] = pack_bf16x2(featmap(f.z), featmap(f.w));
        }
        uint4* dst = (uint4*)&qU[qr][(t & 1) * 16];
        dst[0] = make_uint4(q[0],  q[1],  q[2],  q[3]);
        dst[1] = make_uint4(q[4],  q[5],  q[6],  q[7]);
        dst[2] = make_uint4(q[8],  q[9],  q[10], q[11]);
        dst[3] = make_uint4(q[12], q[13], q[14], q[15]);
    }
    __syncthreads();

    const int wave = t >> 6;
    const int lane = t & 63;
    const int fr = lane & 15;
    const int fk = lane >> 4;

    s16x8 bF[4][2], kF[2];
#pragma unroll
    for (int mt = 0; mt < 4; ++mt)
#pragma unroll
        for (int kk = 0; kk < 2; ++kk)
            bF[mt][kk] = *(const s16x8*)&kvU[mt * 16 + fr][kk * 16 + fk * 4];
#pragma unroll
    for (int kk = 0; kk < 2; ++kk)
        kF[kk] = *(const s16x8*)&ksU[kk * 16 + fk * 4];

    f32x4 acc[2][4];
    f32x4 zac[2];
#pragma unroll
    for (int lt = 0; lt < 2; ++lt) {
        zac[lt] = (f32x4){0.f, 0.f, 0.f, 0.f};
#pragma unroll
        for (int mt = 0; mt < 4; ++mt) acc[lt][mt] = (f32x4){0.f, 0.f, 0.f, 0.f};
    }

#pragma unroll
    for (int kk = 0; kk < 2; ++kk) {
#pragma unroll
        for (int lt = 0; lt < 2; ++lt) {
            s16x8 A = *(const s16x8*)&qU[wave * 32 + lt * 16 + fr][kk * 16 + fk * 4];
            zac[lt] = __builtin_amdgcn_mfma_f32_16x16x32_bf16(A, kF[kk], zac[lt], 0, 0, 0);
#pragma unroll
            for (int mt = 0; mt < 4; ++mt)
                acc[lt][mt] = __builtin_amdgcn_mfma_f32_16x16x32_bf16(
                    A, bF[mt][kk], acc[lt][mt], 0, 0, 0);
        }
    }

#pragma unroll
    for (int lt = 0; lt < 2; ++lt) {
#pragma unroll
        for (int reg = 0; reg < 4; ++reg) {
            const int row = blockIdx.x * 128 + wave * 32 + lt * 16 + fk * 4 + reg;
            const float z = 1.0f / (zac[lt][reg] + EPSF);
            float* orow = out + (((size_t)n * LDIM + row) * HDIM + h) * DDIM;
#pragma unroll
            for (int mt = 0; mt < 4; ++mt)
                orow[mt * 16 + fr] = acc[lt][mt][reg] * z;
        }
    }
}

extern "C" void kernel_launch(void* const* d_in, const int* in_sizes, int n_in,
                              void* d_out, int out_size, void* d_ws, size_t ws_size,
                              hipStream_t stream) {
    const float* Q = (const float*)d_in[0];
    const float* K = (const float*)d_in[1];
    const float* V = (const float*)d_in[2];
    float* out = (float*)d_out;
    float* ws  = (float*)d_ws;

    int chunks = 32;                       // one block per chunk now
    while (chunks > 4 &&
           (size_t)NHEADPAIR * chunks * KVSZ * sizeof(float)
             + (size_t)NHEADPAIR * KVSZ * sizeof(unsigned short) > ws_size)
        chunks >>= 1;
    const int rowsPerBlock = LDIM / chunks;   // 256 at chunks=32; /TROWS integral

    float* part = ws;
    unsigned short* kvh = (unsigned short*)(ws + (size_t)NHEADPAIR * chunks * KVSZ);

    dim3 g1(chunks, NHEADPAIR);
    kv_mfma_kernel<<<g1, 256, 0, stream>>>(K, V, part, chunks, rowsPerBlock);
    dim3 gr((KVSZ + 255) / 256, NHEADPAIR);
    kv_reduce_kernel<<<gr, 256, 0, stream>>>(part, kvh, chunks);
    dim3 g2(LDIM / 128, NHEADPAIR);
    attn_mfma_kernel<<<g2, 256, 0, stream>>>(Q, kvh, out);
}

// Round 12
// 146.100 us; speedup vs baseline: 2.6070x; 1.0014x over previous
//
#include <hip/hip_runtime.h>
#include <hip/hip_bf16.h>

#define LDIM 8192
#define HDIM 16
#define DDIM 64
#define NHEADPAIR 64          // N*H
#define ROWSTRIDE 1024        // H*D floats between consecutive l for fixed h
#define KVSZ 4160             // 64*64 KV + 64 ksum
#define EPSF 1e-6f
#define TROWS 32              // s-rows per staged tile

typedef float f32x4 __attribute__((ext_vector_type(4)));
typedef short s16x8 __attribute__((ext_vector_type(8)));   // 8 bf16 (4 VGPRs)

__device__ __forceinline__ float featmap(float x) {
    // elu(x)+1 : x>0 -> x+1 ; x<=0 -> exp(x)
    return x > 0.0f ? x + 1.0f : __expf(x);
}

__device__ __forceinline__ unsigned int pack_bf16x2(float a, float b) {
    union { __hip_bfloat162 h; unsigned int u; } x;
    x.h = __float22bfloat162_rn(make_float2(a, b));   // elem0 -> low 16 bits
    return x.u;
}

// swizzle: XOR bits 2-3 of the s-pair index with d bits 3-4 (16B-aligned-preserving)
__device__ __forceinline__ int swz(int d) { return ((d >> 3) & 3) << 2; }

// ---------------- Phase 1 (MFMA): partial KV[d][m], Ksum[d] per (n,h,chunk) ---------
// GRID ORIENTATION: x = nh (fastest), y = chunk. All 16 heads of one n are then
// co-resident over the SAME l-range, so their interleaved 256B segments cover DRAM
// pages densely (attn_mfma demonstrates ~4.5TB/s effective with this orientation;
// the old orientation measured 1.5TB/s = classic 256B/4KB page-inefficiency).
__global__ __launch_bounds__(256) void kv_mfma_kernel(
    const float* __restrict__ Kp, const float* __restrict__ Vp,
    float* __restrict__ part, int chunks, int rowsPerBlock)
{
    __shared__ unsigned int KT[2][64 * 16];   // [d][16 s-pair uints] (swizzled)
    __shared__ unsigned int VT[2][64 * 16];   // [m][16 s-pair uints]

    const int nh   = blockIdx.x;              // FASTEST: heads co-resident
    const int ch   = blockIdx.y;              // l-chunk
    const int n    = nh >> 4;
    const int h    = nh & 15;
    const int t    = threadIdx.x;
    const int wave = t >> 6;
    const int lane = t & 63;

    const size_t base = (((size_t)n * LDIM) * HDIM + h) * DDIM
                      + (size_t)ch * rowsPerBlock * ROWSTRIDE;

    // staging map: threads 0-127 stage K (featmap applied), 128-255 stage V.
    const bool isK = (t < 128);
    const int  u   = t & 127;
    const int  dg  = u & 7;          // col-group: cols dg*8 .. dg*8+7
    const int  rp  = u >> 3;         // s-pair 0..15 (rows 2rp, 2rp+1)
    const float* Sb = (isK ? Kp : Vp) + base + (size_t)(2 * rp) * ROWSTRIDE + dg * 8;

    const int NT = rowsPerBlock / TROWS;

    f32x4 acc[4];
    f32x4 zac;
#pragma unroll
    for (int mt = 0; mt < 4; ++mt) acc[mt] = (f32x4){0.f, 0.f, 0.f, 0.f};
    zac = (f32x4){0.f, 0.f, 0.f, 0.f};

    s16x8 ones;
#pragma unroll
    for (int i = 0; i < 8; ++i) ones[i] = (short)0x3F80;   // bf16 1.0

    const int fr = lane & 15;
    const int fk = lane >> 4;
    const int d0 = wave * 16;
    const int raddr = (d0 + fr) * 16 + ((fk * 4) ^ swz(d0 + fr));

    float4 a0, a1, b0, b1;
    a0 = *(const float4*)(Sb);
    a1 = *(const float4*)(Sb + 4);
    b0 = *(const float4*)(Sb + ROWSTRIDE);
    b1 = *(const float4*)(Sb + ROWSTRIDE + 4);
    {
        unsigned int* T = isK ? &KT[0][0] : &VT[0][0];
        float fa[8] = { a0.x, a0.y, a0.z, a0.w, a1.x, a1.y, a1.z, a1.w };
        float fb[8] = { b0.x, b0.y, b0.z, b0.w, b1.x, b1.y, b1.z, b1.w };
        if (isK) {
#pragma unroll
            for (int j = 0; j < 8; ++j) { fa[j] = featmap(fa[j]); fb[j] = featmap(fb[j]); }
        }
#pragma unroll
        for (int j = 0; j < 8; ++j) {
            const int d = dg * 8 + j;
            T[d * 16 + (rp ^ swz(d))] = pack_bf16x2(fa[j], fb[j]);
        }
    }
    __syncthreads();

    int buf = 0;
    for (int tt = 0; tt < NT; ++tt) {
        const bool more = (tt + 1 < NT);
        if (more) {
            const float* S = Sb + (size_t)(tt + 1) * TROWS * ROWSTRIDE;
            a0 = *(const float4*)(S);
            a1 = *(const float4*)(S + 4);
            b0 = *(const float4*)(S + ROWSTRIDE);
            b1 = *(const float4*)(S + ROWSTRIDE + 4);
        }

        // ---- compute current tile: 5 ds_read_b128 + 5 MFMAs per wave ----
        {
            s16x8 A = *(const s16x8*)&KT[buf][raddr];
            zac = __builtin_amdgcn_mfma_f32_16x16x32_bf16(A, ones, zac, 0, 0, 0);
#pragma unroll
            for (int mt = 0; mt < 4; ++mt) {
                const int m = mt * 16 + fr;
                s16x8 B = *(const s16x8*)&VT[buf][m * 16 + ((fk * 4) ^ swz(m))];
                acc[mt] = __builtin_amdgcn_mfma_f32_16x16x32_bf16(A, B, acc[mt], 0, 0, 0);
            }
        }

        // ---- transform + write next tile into other buffer ----
        if (more) {
            unsigned int* T = isK ? &KT[buf ^ 1][0] : &VT[buf ^ 1][0];
            float fa[8] = { a0.x, a0.y, a0.z, a0.w, a1.x, a1.y, a1.z, a1.w };
            float fb[8] = { b0.x, b0.y, b0.z, b0.w, b1.x, b1.y, b1.z, b1.w };
            if (isK) {
#pragma unroll
                for (int j = 0; j < 8; ++j) { fa[j] = featmap(fa[j]); fb[j] = featmap(fb[j]); }
            }
#pragma unroll
            for (int j = 0; j < 8; ++j) {
                const int d = dg * 8 + j;
                T[d * 16 + (rp ^ swz(d))] = pack_bf16x2(fa[j], fb[j]);
            }
        }
        __syncthreads();
        buf ^= 1;
    }

    float* p = part + (size_t)(nh * chunks + ch) * KVSZ;
#pragma unroll
    for (int mt = 0; mt < 4; ++mt) {
#pragma unroll
        for (int reg = 0; reg < 4; ++reg) {
            p[(d0 + fk * 4 + reg) * 64 + mt * 16 + fr] = acc[mt][reg];
        }
    }
    if (fr == 0) {
#pragma unroll
        for (int reg = 0; reg < 4; ++reg)
            p[4096 + d0 + fk * 4 + reg] = zac[reg];
    }
}

// ---------------- Phase 1b: reduce partials, emit bf16 KV + ksum --------------------
__global__ __launch_bounds__(256) void kv_reduce_kernel(
    const float* __restrict__ part, unsigned short* __restrict__ kvh, int chunks)
{
    const int nh = blockIdx.y;
    const int e  = blockIdx.x * 256 + threadIdx.x;
    if (e >= KVSZ) return;
    float s = 0.0f;
    for (int c = 0; c < chunks; ++c)
        s += part[(size_t)(nh * chunks + c) * KVSZ + e];
    union { __hip_bfloat16 h; unsigned short u; } cv;
    cv.h = __float2bfloat16(s);
    kvh[(size_t)nh * KVSZ + e] = cv.u;
}

// ---------------- Phase 2 (MFMA): out[l][m] = Z * sum_d fmQ[l][d] * KV[m][d] --------
// Unchanged (validated; runs at ~effective-BW floor).
__global__ __launch_bounds__(256) void attn_mfma_kernel(
    const float* __restrict__ Qp, const unsigned short* __restrict__ kvh,
    float* __restrict__ out)
{
    __shared__ unsigned int kvU[64][36];
    __shared__ unsigned int ksU[36];
    __shared__ unsigned int qU[128][36];

    const int nh = blockIdx.y;
    const int n  = nh >> 4;
    const int h  = nh & 15;
    const int t  = threadIdx.x;

    {
        const unsigned int* kvg = (const unsigned int*)(kvh + (size_t)nh * KVSZ);
        const int r  = t >> 2;
        const int c0 = (t & 3) * 8;
        uint4 x = *(const uint4*)(kvg + r * 32 + c0);
        uint4 y = *(const uint4*)(kvg + r * 32 + c0 + 4);
        *(uint4*)&kvU[r][c0]     = x;
        *(uint4*)&kvU[r][c0 + 4] = y;
        if (t < 32) ksU[t] = kvg[2048 + t];
    }

    {
        const int qr = t >> 1;
        const float* qg = Qp + ((((size_t)n * LDIM) + (size_t)blockIdx.x * 128 + qr)
                                * HDIM + h) * DDIM + (t & 1) * 32;
        unsigned int q[16];
#pragma unroll
        for (int j = 0; j < 8; ++j) {
            float4 f = *(const float4*)(qg + j * 4);
            q[2 * j]     = pack_bf16x2(featmap(f.x), featmap(f.y));
            q[2 * j + 1] = pack_bf16x2(featmap(f.z), featmap(f.w));
        }
        uint4* dst = (uint4*)&qU[qr][(t & 1) * 16];
        dst[0] = make_uint4(q[0],  q[1],  q[2],  q[3]);
        dst[1] = make_uint4(q[4],  q[5],  q[6],  q[7]);
        dst[2] = make_uint4(q[8],  q[9],  q[10], q[11]);
        dst[3] = make_uint4(q[12], q[13], q[14], q[15]);
    }
    __syncthreads();

    const int wave = t >> 6;
    const int lane = t & 63;
    const int fr = lane & 15;
    const int fk = lane >> 4;

    s16x8 bF[4][2], kF[2];
#pragma unroll
    for (int mt = 0; mt < 4; ++mt)
#pragma unroll
        for (int kk = 0; kk < 2; ++kk)
            bF[mt][kk] = *(const s16x8*)&kvU[mt * 16 + fr][kk * 16 + fk * 4];
#pragma unroll
    for (int kk = 0; kk < 2; ++kk)
        kF[kk] = *(const s16x8*)&ksU[kk * 16 + fk * 4];

    f32x4 acc[2][4];
    f32x4 zac[2];
#pragma unroll
    for (int lt = 0; lt < 2; ++lt) {
        zac[lt] = (f32x4){0.f, 0.f, 0.f, 0.f};
#pragma unroll
        for (int mt = 0; mt < 4; ++mt) acc[lt][mt] = (f32x4){0.f, 0.f, 0.f, 0.f};
    }

#pragma unroll
    for (int kk = 0; kk < 2; ++kk) {
#pragma unroll
        for (int lt = 0; lt < 2; ++lt) {
            s16x8 A = *(const s16x8*)&qU[wave * 32 + lt * 16 + fr][kk * 16 + fk * 4];
            zac[lt] = __builtin_amdgcn_mfma_f32_16x16x32_bf16(A, kF[kk], zac[lt], 0, 0, 0);
#pragma unroll
            for (int mt = 0; mt < 4; ++mt)
                acc[lt][mt] = __builtin_amdgcn_mfma_f32_16x16x32_bf16(
                    A, bF[mt][kk], acc[lt][mt], 0, 0, 0);
        }
    }

#pragma unroll
    for (int lt = 0; lt < 2; ++lt) {
#pragma unroll
        for (int reg = 0; reg < 4; ++reg) {
            const int row = blockIdx.x * 128 + wave * 32 + lt * 16 + fk * 4 + reg;
            const float z = 1.0f / (zac[lt][reg] + EPSF);
            float* orow = out + (((size_t)n * LDIM + row) * HDIM + h) * DDIM;
#pragma unroll
            for (int mt = 0; mt < 4; ++mt)
                orow[mt * 16 + fr] = acc[lt][mt][reg] * z;
        }
    }
}

extern "C" void kernel_launch(void* const* d_in, const int* in_sizes, int n_in,
                              void* d_out, int out_size, void* d_ws, size_t ws_size,
                              hipStream_t stream) {
    const float* Q = (const float*)d_in[0];
    const float* K = (const float*)d_in[1];
    const float* V = (const float*)d_in[2];
    float* out = (float*)d_out;
    float* ws  = (float*)d_ws;

    int chunks = 32;
    while (chunks > 4 &&
           (size_t)NHEADPAIR * chunks * KVSZ * sizeof(float)
             + (size_t)NHEADPAIR * KVSZ * sizeof(unsigned short) > ws_size)
        chunks >>= 1;
    const int rowsPerBlock = LDIM / chunks;

    float* part = ws;
    unsigned short* kvh = (unsigned short*)(ws + (size_t)NHEADPAIR * chunks * KVSZ);

    dim3 g1(NHEADPAIR, chunks);          // x = nh fastest -> heads co-resident
    kv_mfma_kernel<<<g1, 256, 0, stream>>>(K, V, part, chunks, rowsPerBlock);
    dim3 gr((KVSZ + 255) / 256, NHEADPAIR);
    kv_reduce_kernel<<<gr, 256, 0, stream>>>(part, kvh, chunks);
    dim3 g2(LDIM / 128, NHEADPAIR);
    attn_mfma_kernel<<<g2, 256, 0, stream>>>(Q, kvh, out);
}